// Round 7
// baseline (181.660 us; speedup 1.0000x reference)
//
#include <hip/hip_runtime.h>
#include <math.h>

#define N_IN   2048
#define N_OUT  2048
#define BATCH  64
#define NEG_FILL (-1e9f)
#define TEMP   0.1f
#define INV_TEMP 10.0f
#define NBLK   256       // grid size; <= co-resident capacity (2 blocks/CU * 256 CU)
#define ROWS_PB 8        // mask rows per block   (256*8 = 2048)
#define COLS_PB 8        // xT columns per block  (256*8 = 2048)
#define MAXH   64        // max entries per half-row segment (mean 7.5)

// ws word layout:
//   [0]        int barrier counter (hipMemsetAsync -> 0 every launch)
//   [8..71]    row sums of x
//   [72..135]  row absmax of x
//   [192..]    xT[2048][64]
#define WS_CTR   0
#define WS_SUM   8
#define WS_AMAX  72
#define WS_XT    192

// ---------------------------------------------------------------------------
// Single fused kernel. 256 blocks x 1024 threads (16 waves), all co-resident.
//  phase 1 (no cross-block deps):
//    waves 0..15 : ballot-compact half-row (row o0+(wv>>1), half wv&1) of the
//                  mask into a wave-private LDS CSR segment (idx, ew=exp(w/T))
//    wave 13 (blk<64): row-stats (sum, absmax) of x row blk -> ws
//    waves 14,15 : transpose 8 x-columns of this block into ws xT[i][b]
//  device spin-barrier: arrival = one release fetch_add per block;
//  poll = atomic LOADS (broadcastable, no RMW storm) + s_sleep backoff.
//  phase 2: wave wv dots its OWN segment against xT (lane = batch), halves
//           merge in LDS, log, staged contiguous write of out[:, o0..o0+7].
// ---------------------------------------------------------------------------
__global__ __launch_bounds__(1024) void fused_kernel(const float* __restrict__ x,
                                                     const float* __restrict__ w,
                                                     const float* __restrict__ mask,
                                                     float* __restrict__ ws,
                                                     float* __restrict__ out) {
    const int tid  = threadIdx.x;
    const int wv   = tid >> 6;          // 0..15
    const int lane = tid & 63;
    const int blk  = blockIdx.x;
    const int o0   = blk * ROWS_PB;

    __shared__ int   s_idx[16][MAXH];
    __shared__ float s_ew [16][MAXH];
    __shared__ int   s_cnt[16];
    __shared__ float s_acc[16][BATCH];
    __shared__ float s_res[ROWS_PB][BATCH + 1];

    // ---------------- phase 1a: compaction of this wave's half-row ----------
    const int row = o0 + (wv >> 1);
    const int hh  = wv & 1;
    const float4* mrow = reinterpret_cast<const float4*>(mask + (size_t)row * N_IN) + hh * 256;
    const float*  wrow = w + (size_t)row * N_IN;
    const int     ih0  = hh * 1024;
    const unsigned long long below = (1ull << lane) - 1ull;
    int cnt = 0;
#pragma unroll
    for (int r = 0; r < 4; ++r) {
        const float4 mv = mrow[r * 64 + lane];
        const int base  = ih0 + (r * 64 + lane) * 4;
        {
            const bool f = (mv.x != 0.f);
            const unsigned long long bal = __ballot(f);
            if (f) { int p = cnt + __popcll(bal & below);
                     if (p < MAXH) { s_idx[wv][p] = base + 0;
                                     s_ew[wv][p]  = __expf(wrow[base + 0] * INV_TEMP); } }
            cnt += __popcll(bal);
        }
        {
            const bool f = (mv.y != 0.f);
            const unsigned long long bal = __ballot(f);
            if (f) { int p = cnt + __popcll(bal & below);
                     if (p < MAXH) { s_idx[wv][p] = base + 1;
                                     s_ew[wv][p]  = __expf(wrow[base + 1] * INV_TEMP); } }
            cnt += __popcll(bal);
        }
        {
            const bool f = (mv.z != 0.f);
            const unsigned long long bal = __ballot(f);
            if (f) { int p = cnt + __popcll(bal & below);
                     if (p < MAXH) { s_idx[wv][p] = base + 2;
                                     s_ew[wv][p]  = __expf(wrow[base + 2] * INV_TEMP); } }
            cnt += __popcll(bal);
        }
        {
            const bool f = (mv.w != 0.f);
            const unsigned long long bal = __ballot(f);
            if (f) { int p = cnt + __popcll(bal & below);
                     if (p < MAXH) { s_idx[wv][p] = base + 3;
                                     s_ew[wv][p]  = __expf(wrow[base + 3] * INV_TEMP); } }
            cnt += __popcll(bal);
        }
    }
    cnt = min(cnt, MAXH);
    if (lane == 0) s_cnt[wv] = cnt;

    // ---------------- phase 1b: x-derived extras ----------------------------
    if (wv == 13 && blk < 64) {
        const float4* xr = reinterpret_cast<const float4*>(x + (size_t)blk * N_IN);
        float sum = 0.f, amax = 0.f;
#pragma unroll
        for (int r = 0; r < 8; ++r) {
            const float4 v = xr[r * 64 + lane];
            sum += v.x + v.y + v.z + v.w;
            amax = fmaxf(amax, fmaxf(fmaxf(fabsf(v.x), fabsf(v.y)),
                                     fmaxf(fabsf(v.z), fabsf(v.w))));
        }
        for (int off = 32; off; off >>= 1) {
            sum += __shfl_xor(sum, off);
            amax = fmaxf(amax, __shfl_xor(amax, off));
        }
        if (lane == 0) { ws[WS_SUM + blk] = sum; ws[WS_AMAX + blk] = amax; }
    }
    if (wv >= 14) {
        const int i0 = blk * COLS_PB + (wv - 14) * 4;
#pragma unroll
        for (int c = 0; c < 4; ++c) {
            const float v = x[(size_t)lane * N_IN + i0 + c];
            ws[WS_XT + (size_t)(i0 + c) * 64 + lane] = v;
        }
    }

    // ---------------- device-wide barrier (load-poll, no RMW storm) ---------
    __threadfence();
    __syncthreads();
    if (tid == 0) {
        int* ctr = reinterpret_cast<int*>(ws) + WS_CTR;
        __hip_atomic_fetch_add(ctr, 1, __ATOMIC_RELEASE, __HIP_MEMORY_SCOPE_AGENT);
        while (__hip_atomic_load(ctr, __ATOMIC_ACQUIRE, __HIP_MEMORY_SCOPE_AGENT) < NBLK) {
            __builtin_amdgcn_s_sleep(16);
        }
    }
    __syncthreads();
    __threadfence();

    // ---------------- phase 2: sparse dot ----------------------------------
    const float sum_l = ws[WS_SUM + lane];
    float mx = ws[WS_AMAX + lane];
    for (int off = 32; off; off >>= 1) mx = fmaxf(mx, __shfl_xor(mx, off));
    const float dinv = 1.0f / (mx + 1e-6f);
    const float cons = sum_l * dinv * (1.0f / (float)N_IN);

    const float* xT = ws + WS_XT;
    float acc = 0.f;
    int k = 0;
    for (; k + 2 <= cnt; k += 2) {
        const int   i0_ = s_idx[wv][k + 0], i1_ = s_idx[wv][k + 1];
        const float e0  = s_ew[wv][k + 0],  e1  = s_ew[wv][k + 1];
        const float v0  = xT[(size_t)i0_ * 64 + lane] * dinv;
        const float v1  = xT[(size_t)i1_ * 64 + lane] * dinv;
        const float g0  = (fabsf(v0 - cons) < 1.0f) ? v0 : 0.f;
        const float g1  = (fabsf(v1 - cons) < 1.0f) ? v1 : 0.f;
        acc += e0 * __expf(g0 * INV_TEMP);
        acc += e1 * __expf(g1 * INV_TEMP);
    }
    if (k < cnt) {
        const int   i_ = s_idx[wv][k];
        const float e_ = s_ew[wv][k];
        const float v  = xT[(size_t)i_ * 64 + lane] * dinv;
        const float g  = (fabsf(v - cons) < 1.0f) ? v : 0.f;
        acc += e_ * __expf(g * INV_TEMP);
    }

    s_acc[wv][lane] = acc;
    __syncthreads();
    if (hh == 0) {
        const float total = s_acc[wv][lane] + s_acc[wv + 1][lane];
        const int   tcnt  = s_cnt[wv] + s_cnt[wv + 1];
        const float res   = (tcnt > 0) ? TEMP * logf(total)
                                       : NEG_FILL + TEMP * logf((float)N_IN);
        s_res[wv >> 1][lane] = res;
    }
    __syncthreads();
    if (tid < 512) {
        const int b = tid >> 3, c = tid & 7;   // 32B contiguous per batch
        out[(size_t)b * N_OUT + o0 + c] = s_res[c][b];
    }
}

extern "C" void kernel_launch(void* const* d_in, const int* in_sizes, int n_in,
                              void* d_out, int out_size, void* d_ws, size_t ws_size,
                              hipStream_t stream) {
    const float* x    = (const float*)d_in[0];
    const float* wgt  = (const float*)d_in[1];
    const float* mask = (const float*)d_in[2];
    float* out = (float*)d_out;
    float* ws  = (float*)d_ws;

    // zero the barrier counter (graph-capturable memset node)
    hipMemsetAsync(d_ws, 0, 4, stream);
    fused_kernel<<<NBLK, 1024, 0, stream>>>(x, wgt, mask, ws, out);
}

// Round 8
// 23.393 us; speedup vs baseline: 7.7655x; 7.7655x over previous
//
#include <hip/hip_runtime.h>
#include <math.h>

#define N_IN   2048
#define N_OUT  2048
#define BATCH  64
#define NEG_FILL (-1e9f)
#define TEMP   0.1f
#define INV_TEMP 10.0f
#define NBLK   256       // 2048 rows / 8 rows per block
#define ROWS_PB 8
#define MAXH   64        // max entries per half-row segment (mean 7.5)

// ---------------------------------------------------------------------------
// Single fused kernel, NO grid sync, no workspace. 256 blocks x 1024 threads.
//  phase A: wave wv ballot-compacts mask half-row (row o0+(wv>>1), half wv&1)
//           into a wave-private LDS CSR segment (idx, ew=exp(w/T)).
//  phase C: wave wv streams x rows 4wv..4wv+3 (coalesced float4) and computes
//           per-row sum + absmax -> LDS. (Every block recomputes stats from
//           the 512KB x — L2-resident after the first pass per XCD; this is
//           what replaces the pathological device-wide spin barrier.)
//  one __syncthreads.
//  phase D: per-wave sparse dot (lane = batch): gather x[lane][i] from
//           L2-hot x, gate, acc += exp(w/T)*exp(g/T). Halves merge in LDS,
//           log, staged 32B-contiguous write of out[:, o0..o0+7].
// ---------------------------------------------------------------------------
__global__ __launch_bounds__(1024) void fused_kernel(const float* __restrict__ x,
                                                     const float* __restrict__ w,
                                                     const float* __restrict__ mask,
                                                     float* __restrict__ out) {
    const int tid  = threadIdx.x;
    const int wv   = tid >> 6;          // 0..15
    const int lane = tid & 63;
    const int blk  = blockIdx.x;
    const int o0   = blk * ROWS_PB;

    __shared__ int   s_idx[16][MAXH];
    __shared__ float s_ew [16][MAXH];
    __shared__ int   s_cnt[16];
    __shared__ float s_rsum[BATCH];
    __shared__ float s_ramax[BATCH];
    __shared__ float s_acc[16][BATCH];
    __shared__ float s_res[ROWS_PB][BATCH + 1];

    // ---------------- phase A: compaction of this wave's half-row -----------
    const int row = o0 + (wv >> 1);
    const int hh  = wv & 1;
    const float4* mrow = reinterpret_cast<const float4*>(mask + (size_t)row * N_IN) + hh * 256;
    const float*  wrow = w + (size_t)row * N_IN;
    const int     ih0  = hh * 1024;
    const unsigned long long below = (1ull << lane) - 1ull;
    int cnt = 0;
#pragma unroll
    for (int r = 0; r < 4; ++r) {
        const float4 mv = mrow[r * 64 + lane];
        const int base  = ih0 + (r * 64 + lane) * 4;
        {
            const bool f = (mv.x != 0.f);
            const unsigned long long bal = __ballot(f);
            if (f) { int p = cnt + __popcll(bal & below);
                     if (p < MAXH) { s_idx[wv][p] = base + 0;
                                     s_ew[wv][p]  = __expf(wrow[base + 0] * INV_TEMP); } }
            cnt += __popcll(bal);
        }
        {
            const bool f = (mv.y != 0.f);
            const unsigned long long bal = __ballot(f);
            if (f) { int p = cnt + __popcll(bal & below);
                     if (p < MAXH) { s_idx[wv][p] = base + 1;
                                     s_ew[wv][p]  = __expf(wrow[base + 1] * INV_TEMP); } }
            cnt += __popcll(bal);
        }
        {
            const bool f = (mv.z != 0.f);
            const unsigned long long bal = __ballot(f);
            if (f) { int p = cnt + __popcll(bal & below);
                     if (p < MAXH) { s_idx[wv][p] = base + 2;
                                     s_ew[wv][p]  = __expf(wrow[base + 2] * INV_TEMP); } }
            cnt += __popcll(bal);
        }
        {
            const bool f = (mv.w != 0.f);
            const unsigned long long bal = __ballot(f);
            if (f) { int p = cnt + __popcll(bal & below);
                     if (p < MAXH) { s_idx[wv][p] = base + 3;
                                     s_ew[wv][p]  = __expf(wrow[base + 3] * INV_TEMP); } }
            cnt += __popcll(bal);
        }
    }
    cnt = min(cnt, MAXH);
    if (lane == 0) s_cnt[wv] = cnt;

    // ---------------- phase C: per-block stats over ALL of x ----------------
    // wave wv handles x rows 4wv..4wv+3, coalesced float4, shfl-reduce each.
#pragma unroll
    for (int r = 0; r < 4; ++r) {
        const int b = wv * 4 + r;
        const float4* xr = reinterpret_cast<const float4*>(x + (size_t)b * N_IN);
        float sum = 0.f, amax = 0.f;
#pragma unroll
        for (int it = 0; it < 8; ++it) {
            const float4 v = xr[it * 64 + lane];
            sum += v.x + v.y + v.z + v.w;
            amax = fmaxf(amax, fmaxf(fmaxf(fabsf(v.x), fabsf(v.y)),
                                     fmaxf(fabsf(v.z), fabsf(v.w))));
        }
        for (int off = 32; off; off >>= 1) {
            sum += __shfl_xor(sum, off);
            amax = fmaxf(amax, __shfl_xor(amax, off));
        }
        if (lane == 0) { s_rsum[b] = sum; s_ramax[b] = amax; }
    }
    __syncthreads();

    // ---------------- stats finalize (every wave, redundant) ----------------
    float mx = s_ramax[lane];
    for (int off = 32; off; off >>= 1) mx = fmaxf(mx, __shfl_xor(mx, off));
    const float dinv = 1.0f / (mx + 1e-6f);
    const float cons = s_rsum[lane] * dinv * (1.0f / (float)N_IN);   // lane = batch

    // ---------------- phase D: sparse dot (lane = batch) --------------------
    const float* xrow = x + (size_t)lane * N_IN;   // this lane's batch row
    float acc = 0.f;
    int k = 0;
    for (; k + 2 <= cnt; k += 2) {
        const int   i0_ = s_idx[wv][k + 0], i1_ = s_idx[wv][k + 1];
        const float e0  = s_ew[wv][k + 0],  e1  = s_ew[wv][k + 1];
        const float v0  = xrow[i0_] * dinv;
        const float v1  = xrow[i1_] * dinv;
        const float g0  = (fabsf(v0 - cons) < 1.0f) ? v0 : 0.f;
        const float g1  = (fabsf(v1 - cons) < 1.0f) ? v1 : 0.f;
        acc += e0 * __expf(g0 * INV_TEMP);
        acc += e1 * __expf(g1 * INV_TEMP);
    }
    if (k < cnt) {
        const int   i_ = s_idx[wv][k];
        const float e_ = s_ew[wv][k];
        const float v  = xrow[i_] * dinv;
        const float g  = (fabsf(v - cons) < 1.0f) ? v : 0.f;
        acc += e_ * __expf(g * INV_TEMP);
    }

    s_acc[wv][lane] = acc;
    __syncthreads();
    if (hh == 0) {
        const float total = s_acc[wv][lane] + s_acc[wv + 1][lane];
        const int   tcnt  = s_cnt[wv] + s_cnt[wv + 1];
        const float res   = (tcnt > 0) ? TEMP * logf(total)
                                       : NEG_FILL + TEMP * logf((float)N_IN);
        s_res[wv >> 1][lane] = res;
    }
    __syncthreads();
    if (tid < 512) {
        const int b = tid >> 3, c = tid & 7;   // 32B contiguous per batch
        out[(size_t)b * N_OUT + o0 + c] = s_res[c][b];
    }
}

extern "C" void kernel_launch(void* const* d_in, const int* in_sizes, int n_in,
                              void* d_out, int out_size, void* d_ws, size_t ws_size,
                              hipStream_t stream) {
    const float* x    = (const float*)d_in[0];
    const float* wgt  = (const float*)d_in[1];
    const float* mask = (const float*)d_in[2];
    float* out = (float*)d_out;
    (void)d_ws; (void)ws_size;

    fused_kernel<<<NBLK, 1024, 0, stream>>>(x, wgt, mask, out);
}